// Round 3
// baseline (129.037 us; speedup 1.0000x reference)
//
#include <hip/hip_runtime.h>

// VectorQuantizer: x [32,64,64,64] f32, emb [512,64] f32 -> out [32,64,64,64] f32
// R13: occupancy + parallel-rescore restructure of the R12 swapped screen.
//  - scores never fully materialized: keep mm4[mt][nt]=min_r(acc) only
//    (16 regs vs 64 -> frees the AGPR-resident s[] that capped us at
//    ~4 waves/SIMD). Detect at cell granularity; triggered cell enqueues
//    its 4 codes (superset of R12's per-r candidate set -> safe).
//  - wave-parallel rescore: popcount+shfl prefix compaction into per-wave
//    LDS queue, lanes rescore in parallel rounds (serial fallback past QW).
//    No extra barrier: queue is wave-synchronous (explicit lgkmcnt(0)).
//  - xsq computed by waves 4-7 (16 lanes each; row-pair bank aliasing is
//    2-way = free) so no single wave delays barrier 2; e_sq staged to LDS
//    (lesq) freeing the esql register prefetch; efr loads split pre/post-B1
//    to cap peak VGPR pressure.
// Exact-score semantics unchanged from R8-R12 (absmax==0): sequential-c fmaf
// dot, pairwise-8 sums, _rn combine, lexicographic (se,k) u64 atomicMin.

#define KNUM 512
#define CDIM 64
#define MPB  64
#define QW   96

typedef __attribute__((ext_vector_type(8))) short bf16x8;
typedef __attribute__((ext_vector_type(4))) float f32x4;

__device__ __forceinline__ unsigned f2bf(float f) {   // RNE f32->bf16
    unsigned u = __float_as_uint(f);
    return (u + 0x7FFFu + ((u >> 16) & 1u)) >> 16;
}
__device__ __forceinline__ unsigned ordf(float f) {   // total-order encode
    unsigned u = __float_as_uint(f);
    return u ^ ((unsigned)(((int)u) >> 31) | 0x80000000u);
}
__device__ __forceinline__ float ordinv(unsigned u) {
    unsigned fb = (u & 0x80000000u) ? (u ^ 0x80000000u) : ~u;
    return __uint_as_float(fb);
}

__device__ __forceinline__ float xsq_pairwise8(const float* xr)   // np order
{
    float r[8];
    {
        const float4 a = *(const float4*)&xr[0];
        const float4 c = *(const float4*)&xr[4];
        r[0] = __fmul_rn(a.x, a.x); r[1] = __fmul_rn(a.y, a.y);
        r[2] = __fmul_rn(a.z, a.z); r[3] = __fmul_rn(a.w, a.w);
        r[4] = __fmul_rn(c.x, c.x); r[5] = __fmul_rn(c.y, c.y);
        r[6] = __fmul_rn(c.z, c.z); r[7] = __fmul_rn(c.w, c.w);
    }
    #pragma unroll
    for (int i = 1; i < 8; ++i) {
        const float4 a = *(const float4*)&xr[8 * i];
        const float4 c = *(const float4*)&xr[8 * i + 4];
        r[0] = __fadd_rn(r[0], __fmul_rn(a.x, a.x));
        r[1] = __fadd_rn(r[1], __fmul_rn(a.y, a.y));
        r[2] = __fadd_rn(r[2], __fmul_rn(a.z, a.z));
        r[3] = __fadd_rn(r[3], __fmul_rn(a.w, a.w));
        r[4] = __fadd_rn(r[4], __fmul_rn(c.x, c.x));
        r[5] = __fadd_rn(r[5], __fmul_rn(c.y, c.y));
        r[6] = __fadd_rn(r[6], __fmul_rn(c.z, c.z));
        r[7] = __fadd_rn(r[7], __fmul_rn(c.w, c.w));
    }
    return __fadd_rn(
        __fadd_rn(__fadd_rn(r[0], r[1]), __fadd_rn(r[2], r[3])),
        __fadd_rn(__fadd_rn(r[4], r[5]), __fadd_rn(r[6], r[7])));
}

__global__ __launch_bounds__(64) void vq_prep(const float* __restrict__ emb,
                                              float* __restrict__ e_sq,
                                              unsigned* __restrict__ ebf)
{
    const int k = blockIdx.x * 64 + threadIdx.x;
    const float* e = emb + k * CDIM;
    float4 f[16];
    #pragma unroll
    for (int i = 0; i < 16; ++i) f[i] = ((const float4*)e)[i];

    float r[8];
    r[0] = __fmul_rn(f[0].x, f[0].x); r[1] = __fmul_rn(f[0].y, f[0].y);
    r[2] = __fmul_rn(f[0].z, f[0].z); r[3] = __fmul_rn(f[0].w, f[0].w);
    r[4] = __fmul_rn(f[1].x, f[1].x); r[5] = __fmul_rn(f[1].y, f[1].y);
    r[6] = __fmul_rn(f[1].z, f[1].z); r[7] = __fmul_rn(f[1].w, f[1].w);
    #pragma unroll
    for (int i = 1; i < 8; ++i) {
        const float4 a = f[2 * i], c = f[2 * i + 1];
        r[0] = __fadd_rn(r[0], __fmul_rn(a.x, a.x));
        r[1] = __fadd_rn(r[1], __fmul_rn(a.y, a.y));
        r[2] = __fadd_rn(r[2], __fmul_rn(a.z, a.z));
        r[3] = __fadd_rn(r[3], __fmul_rn(a.w, a.w));
        r[4] = __fadd_rn(r[4], __fmul_rn(c.x, c.x));
        r[5] = __fadd_rn(r[5], __fmul_rn(c.y, c.y));
        r[6] = __fadd_rn(r[6], __fmul_rn(c.z, c.z));
        r[7] = __fadd_rn(r[7], __fmul_rn(c.w, c.w));
    }
    e_sq[k] = __fadd_rn(
        __fadd_rn(__fadd_rn(r[0], r[1]), __fadd_rn(r[2], r[3])),
        __fadd_rn(__fadd_rn(r[4], r[5]), __fadd_rn(r[6], r[7])));

    // bf16(-2e): exact power-of-2 scale, products are exactly -2x original
    unsigned buf[32];
    #pragma unroll
    for (int i = 0; i < 16; ++i) {
        buf[2 * i]     = f2bf(__fmul_rn(-2.0f, f[i].x))
                       | (f2bf(__fmul_rn(-2.0f, f[i].y)) << 16);
        buf[2 * i + 1] = f2bf(__fmul_rn(-2.0f, f[i].z))
                       | (f2bf(__fmul_rn(-2.0f, f[i].w)) << 16);
    }
    uint4* dst = (uint4*)(ebf + k * 32);
    #pragma unroll
    for (int i = 0; i < 8; ++i) dst[i] = ((const uint4*)buf)[i];
}

__global__ __launch_bounds__(512, 4) void vq_main(const float* __restrict__ x,
                                                  const float* __restrict__ emb,
                                                  const float* __restrict__ e_sq,
                                                  const unsigned* __restrict__ ebf,
                                                  float* __restrict__ out)
{
    __shared__ float    xt[MPB][68];           // 17408 B exact x
    __shared__ _Float16 xbf[MPB][72];          //  9216 B bf16 x (B-frags)
    __shared__ float    axp[MPB][10];          //  2560 B |x| partials
    __shared__ float    margl[MPB];            //   256 B per-pixel margin
    __shared__ float    xsql[MPB];             //   256 B per-pixel ||x||^2
    __shared__ float    lesq[KNUM];            //  2048 B e_sq copy
    __shared__ unsigned pthr[MPB];             //   256 B ordered screen min
    __shared__ unsigned long long bestpk[MPB]; //   512 B
    __shared__ unsigned wq[8][QW];             //  3072 B per-wave cand queues

    const int t    = threadIdx.x;
    const int pix0 = blockIdx.x * MPB;
    const int b    = pix0 >> 12;
    const int hw0  = pix0 & 4095;
    const float* xb = x + ((size_t)b << 18) + hw0;

    const int l    = t & 63;
    const int w    = __builtin_amdgcn_readfirstlane(t >> 6);  // uniform wave id
    const int i15  = l & 15, quad = l >> 4;
    const int nbase = w * 64;

    // ---- issue x staging loads first (HBM/L3, longest latency) ----
    const float* xp = xb + ((size_t)(8 * w) << 12) + l;
    float v[8];
    #pragma unroll
    for (int j = 0; j < 8; ++j) v[j] = xp[(size_t)j << 12];

    // ---- prefetch half the code A-frags (bf16(-2e)) before B1 ----
    bf16x8 efr[4][2];
    #pragma unroll
    for (int mt = 0; mt < 2; ++mt)
        #pragma unroll
        for (int kc = 0; kc < 2; ++kc)
            efr[mt][kc] = *(const bf16x8*)((const char*)ebf
                + (size_t)(nbase + mt * 16 + i15) * 128 + kc * 64 + quad * 16);

    lesq[t] = e_sq[t];                         // KNUM == blockDim
    if (t < MPB) { pthr[t] = 0xFFFFFFFFu; bestpk[t] = ~0ull; }

    // ---- finish staging: f32 + bf16 + |x| partial ----
    {
        *(float4*)&xt[l][8 * w]     = make_float4(v[0], v[1], v[2], v[3]);
        *(float4*)&xt[l][8 * w + 4] = make_float4(v[4], v[5], v[6], v[7]);
        uint4 dp;
        dp.x = f2bf(v[0]) | (f2bf(v[1]) << 16);
        dp.y = f2bf(v[2]) | (f2bf(v[3]) << 16);
        dp.z = f2bf(v[4]) | (f2bf(v[5]) << 16);
        dp.w = f2bf(v[6]) | (f2bf(v[7]) << 16);
        *(uint4*)&xbf[l][8 * w] = dp;
        axp[l][w] = ((fabsf(v[0]) + fabsf(v[1])) + (fabsf(v[2]) + fabsf(v[3])))
                  + ((fabsf(v[4]) + fabsf(v[5])) + (fabsf(v[6]) + fabsf(v[7])));
    }
    __syncthreads();                           // B1

    // ---- second half of A-frags (L2, hides under first MFMA tiles) ----
    #pragma unroll
    for (int mt = 2; mt < 4; ++mt)
        #pragma unroll
        for (int kc = 0; kc < 2; ++kc)
            efr[mt][kc] = *(const bf16x8*)((const char*)ebf
                + (size_t)(nbase + mt * 16 + i15) * 128 + kc * 64 + quad * 16);

    // ---- wave 0: per-pixel margin (cheap) ----
    if (t < MPB) {
        const float ax = ((axp[t][0] + axp[t][1]) + (axp[t][2] + axp[t][3]))
                       + ((axp[t][4] + axp[t][5]) + (axp[t][6] + axp[t][7]));
        margl[t] = fmaf(4.0e-5f, ax, 5.0e-4f);
    }

    // ---- MFMA screen: keep only per-cell min over the 4 acc rows ----
    float mm4[4][4];                           // [mt][nt]
    #pragma unroll
    for (int nt = 0; nt < 4; ++nt) {
        const bf16x8 xf0 = *(const bf16x8*)&xbf[nt * 16 + i15][quad * 8];
        const bf16x8 xf1 = *(const bf16x8*)&xbf[nt * 16 + i15][quad * 8 + 32];
        #pragma unroll
        for (int mt = 0; mt < 4; ++mt) {
            f32x4 acc = *(const f32x4*)&lesq[nbase + mt * 16 + quad * 4];
            acc = __builtin_amdgcn_mfma_f32_16x16x32_bf16(efr[mt][0], xf0, acc, 0, 0, 0);
            acc = __builtin_amdgcn_mfma_f32_16x16x32_bf16(efr[mt][1], xf1, acc, 0, 0, 0);
            mm4[mt][nt] = fminf(fminf(acc[0], acc[1]), fminf(acc[2], acc[3]));
        }
    }
    // per-pixel min over this wave's 64 codes: 3 fmin + 2 shfl per nt
    #pragma unroll
    for (int nt = 0; nt < 4; ++nt) {
        float mv = fminf(fminf(mm4[0][nt], mm4[1][nt]),
                         fminf(mm4[2][nt], mm4[3][nt]));
        mv = fminf(mv, __shfl_xor(mv, 16));
        mv = fminf(mv, __shfl_xor(mv, 32));
        if (quad == 0) atomicMin(&pthr[nt * 16 + i15], ordf(mv));
    }
    // ---- waves 4-7: exact ||x||^2 (16 lanes each; 2-way bank alias = free) ----
    if (w >= 4 && l < 16) {
        const int p = (w - 4) * 16 + l;
        xsql[p] = xsq_pairwise8(xt[p]);
    }
    __syncthreads();                           // B2

    // ---- detect (cell granularity) + wave compaction + parallel rescore ----
    {
        auto rescore = [&](int p2, int k) {
            const float xs = xsql[p2];
            const float* xr = &xt[p2][0];
            const float* er = emb + (size_t)k * CDIM;
            float d = 0.f;
            #pragma unroll
            for (int c4 = 0; c4 < 16; ++c4) {  // sequential-c fmaf = np order
                const float4 xv = *(const float4*)&xr[4 * c4];
                const float4 ev = *(const float4*)&er[4 * c4];
                d = fmaf(xv.x, ev.x, d);
                d = fmaf(xv.y, ev.y, d);
                d = fmaf(xv.z, ev.z, d);
                d = fmaf(xv.w, ev.w, d);
            }
            const float se = __fsub_rn(__fadd_rn(xs, lesq[k]),
                                       __fmul_rn(2.0f, d));
            const unsigned long long pkd =
                ((unsigned long long)ordf(se) << 32) | (unsigned)k;
            atomicMin(&bestpk[p2], pkd);       // lexicographic (se, k)
        };

        float tr[4];
        #pragma unroll
        for (int nt = 0; nt < 4; ++nt)
            tr[nt] = __fadd_rn(ordinv(pthr[nt * 16 + i15]),
                               margl[nt * 16 + i15]);

        unsigned m16 = 0;
        #pragma unroll
        for (int mt = 0; mt < 4; ++mt)
            #pragma unroll
            for (int nt = 0; nt < 4; ++nt)
                if (mm4[mt][nt] < tr[nt])                  // rare
                    m16 |= 1u << (mt * 4 + nt);

        // wave-wide exclusive prefix of candidate-cell counts
        const int cnt = __popc(m16);
        int incl = cnt;
        #pragma unroll
        for (int d = 1; d < 64; d <<= 1) {
            const int y = __shfl_up(incl, d);
            if (l >= d) incl += y;
        }
        int pre = incl - cnt;
        const int total = __shfl(incl, 63);

        unsigned mrem = m16;
        while (mrem) {
            const int bit = __builtin_ctz(mrem);
            mrem &= mrem - 1;
            const int mt = bit >> 2, nt = bit & 3;
            const int p2 = nt * 16 + i15;
            const int k0 = nbase + mt * 16 + quad * 4;
            if (pre < QW)
                wq[w][pre] = ((unsigned)p2 << 16) | (unsigned)k0;
            else {                                         // overflow: serial
                #pragma unroll
                for (int r = 0; r < 4; ++r) rescore(p2, k0 + r);
            }
            ++pre;
        }
        asm volatile("s_waitcnt lgkmcnt(0)" ::: "memory"); // wave-sync queue

        const int nitems = min(total, QW) * 4;
        for (int i = l; i < nitems; i += 64) {             // parallel rounds
            const unsigned e = wq[w][i >> 2];
            rescore((int)(e >> 16), (int)(e & 0xFFFFu) + (i & 3));
        }
    }
    __syncthreads();                           // B3

    // ---- gather winning emb row (bit-exact) -> [B,C,H,W] ----
    {
        const int wi = (int)(bestpk[l] & 0xFFFFu);
        const float* ew = emb + (size_t)wi * CDIM + 8 * w;
        const float4 e0 = *(const float4*)ew;
        const float4 e1 = *(const float4*)(ew + 4);
        float* ob = out + ((size_t)b << 18) + (((size_t)(8 * w)) << 12) + hw0 + l;
        ob[(size_t)0 << 12] = e0.x;
        ob[(size_t)1 << 12] = e0.y;
        ob[(size_t)2 << 12] = e0.z;
        ob[(size_t)3 << 12] = e0.w;
        ob[(size_t)4 << 12] = e1.x;
        ob[(size_t)5 << 12] = e1.y;
        ob[(size_t)6 << 12] = e1.z;
        ob[(size_t)7 << 12] = e1.w;
    }
}

extern "C" void kernel_launch(void* const* d_in, const int* in_sizes, int n_in,
                              void* d_out, int out_size, void* d_ws, size_t ws_size,
                              hipStream_t stream)
{
    const float* x   = (const float*)d_in[0];
    const float* emb = (const float*)d_in[1];
    float* out  = (float*)d_out;
    float*    e_sq = (float*)d_ws;                 // 2 KB
    unsigned* ebf  = (unsigned*)d_ws + KNUM;       // 64 KB bf16(-2e)

    hipLaunchKernelGGL(vq_prep, dim3(KNUM / 64), dim3(64), 0, stream, emb, e_sq, ebf);
    const int nblocks = (32 * 64 * 64) / MPB;      // 2048
    hipLaunchKernelGGL(vq_main, dim3(nblocks), dim3(512), 0, stream,
                       x, emb, e_sq, ebf, out);
}